// Round 1
// baseline (699.241 us; speedup 1.0000x reference)
//
#include <hip/hip_runtime.h>

// ElementwiseTensorProd l=1 outputs, three CG paths:
//   p_01[n,c,r] = z0l[n,r]        * z1r[n,c,r]
//   p_10[n,c,r] = z1l[n,c,r]      * z0r[n,r]
//   p_11[n,c,r] = cross(z1l,z1r)[n,c,r] * 1/sqrt(2)
// Output (N, 3, 3*RANK), channel axis = [p01 | p10 | p11].

#define INV_SQRT2 0.70710678118654752440f

constexpr int N_PTS = 50000;
constexpr int RANK  = 256;
constexpr int R4    = RANK / 4;   // 64 float4 per row — exactly one wave

__device__ __forceinline__ float4 mul4(float4 a, float4 b) {
    return make_float4(a.x * b.x, a.y * b.y, a.z * b.z, a.w * b.w);
}
__device__ __forceinline__ float4 smul4(float4 a, float s) {
    return make_float4(a.x * s, a.y * s, a.z * s, a.w * s);
}
// a*b - c*d, per component (fma for the first product)
__device__ __forceinline__ float4 fms4(float4 a, float4 b, float4 c, float4 d) {
    return make_float4(fmaf(a.x, b.x, -(c.x * d.x)),
                       fmaf(a.y, b.y, -(c.y * d.y)),
                       fmaf(a.z, b.z, -(c.z * d.z)),
                       fmaf(a.w, b.w, -(c.w * d.w)));
}

__global__ __launch_bounds__(256) void etp_o1_kernel(
    const float4* __restrict__ z0l,   // (N, R4)
    const float4* __restrict__ z1l,   // (N, 3, R4)
    const float4* __restrict__ z0r,   // (N, R4)
    const float4* __restrict__ z1r,   // (N, 3, R4)
    float4* __restrict__ out)         // (N, 3, 3*R4)
{
    const int t = blockIdx.x * blockDim.x + threadIdx.x;
    if (t >= N_PTS * R4) return;
    const int n = t >> 6;   // t / 64
    const int r = t & 63;   // t % 64

    const float4 sl = z0l[n * R4 + r];
    const float4 sr = z0r[n * R4 + r];

    const int vbase = n * 3 * R4 + r;
    const float4 lx = z1l[vbase + 0 * R4];
    const float4 ly = z1l[vbase + 1 * R4];
    const float4 lz = z1l[vbase + 2 * R4];
    const float4 rx = z1r[vbase + 0 * R4];
    const float4 ry = z1r[vbase + 1 * R4];
    const float4 rz = z1r[vbase + 2 * R4];

    // cross(l, r) along the c-axis
    const float4 cx = fms4(ly, rz, lz, ry);
    const float4 cy = fms4(lz, rx, lx, rz);
    const float4 cz = fms4(lx, ry, ly, rx);

    // out[(n*3 + c)*3*R4 + path*R4 + r]
    const int obase = n * 3 * (3 * R4) + r;
    // c = 0 (x)
    out[obase + 0 * (3 * R4) + 0 * R4] = mul4(sl, rx);
    out[obase + 0 * (3 * R4) + 1 * R4] = mul4(lx, sr);
    out[obase + 0 * (3 * R4) + 2 * R4] = smul4(cx, INV_SQRT2);
    // c = 1 (y)
    out[obase + 1 * (3 * R4) + 0 * R4] = mul4(sl, ry);
    out[obase + 1 * (3 * R4) + 1 * R4] = mul4(ly, sr);
    out[obase + 1 * (3 * R4) + 2 * R4] = smul4(cy, INV_SQRT2);
    // c = 2 (z)
    out[obase + 2 * (3 * R4) + 0 * R4] = mul4(sl, rz);
    out[obase + 2 * (3 * R4) + 1 * R4] = mul4(lz, sr);
    out[obase + 2 * (3 * R4) + 2 * R4] = smul4(cz, INV_SQRT2);
}

extern "C" void kernel_launch(void* const* d_in, const int* in_sizes, int n_in,
                              void* d_out, int out_size, void* d_ws, size_t ws_size,
                              hipStream_t stream) {
    const float4* z0l = (const float4*)d_in[0];
    const float4* z1l = (const float4*)d_in[1];
    const float4* z0r = (const float4*)d_in[2];
    const float4* z1r = (const float4*)d_in[3];
    float4* out = (float4*)d_out;

    const int total = N_PTS * R4;            // 3,200,000 threads
    const int block = 256;
    const int grid  = (total + block - 1) / block;  // 12500
    etp_o1_kernel<<<grid, block, 0, stream>>>(z0l, z1l, z0r, z1r, out);
}